// Round 6
// baseline (318.759 us; speedup 1.0000x reference)
//
#include <hip/hip_runtime.h>
#include <stdint.h>
#include <stddef.h>

// ---------------------------------------------------------------------------
// BoundingBox loss processor:
//   filter (maxconf > 0.6) -> sort by class-0 score desc (stable, idx asc)
//   -> greedy NMS (IoU > 0.5 suppress) -> per-class top-20 over kept
//   -> smooth-L1 sum + focal CE on (class0 top-20 > 0.5) -> /M
//
// Journal: R10 involved-set greedy. R13 register topk. R14 pre-OR atomics.
// R15 128-row chunks. R17 short wave-0 segment. R18 sort split.
// R19 NULL: no-drain barriers — loads already hidden.
// R20/R21 WIN: DPP wave-OR (ds_bpermute -> VALU DPP), 137->99.8us. k_scan is
// now at the single-CU HBM share (hbm_gbps=24 ~ 6.3TB/s/256): BYTES-bound.
// R22/R23: sparsity gate (mask words mostly zero for random boxes) — k_mask
// emits colNZ[pair][bx]=ballot(word nonzero); k_scan gates each 16B pair
// load on its bit (skipped word==0 -> rem identical). Both runs died at
// container level ("failed twice") with the wave-2 LDS summary pipeline.
// R24: same gate, de-risked delivery — per-thread REGISTER gate with 1-deep
// self-prefetch (nzp for chunk H; nzn=cz[H+1] issued before B1, completes
// under the greedy). No ldsNZ, no cross-wave producer/consumer; k_scan delta
// vs hardware-proven R21 is ~10 lines of pure per-thread code.
// ---------------------------------------------------------------------------

#define NCAP 8192
#define WROW (NCAP / 64)   // 128 u64 words per mask row
#define NBX  (NCAP / 64)   // 128 row-blocks

typedef unsigned long long u64;

// ---------------- workspace layout (all offsets 16-byte aligned) -----------
constexpr size_t OFF_CNT   = 0;                               // 2 x u32: [0]=F, [1]=M
constexpr size_t OFF_KEYS  = 256;                             // u64[NCAP] (psort->merge)
constexpr size_t OFF_SX1   = OFF_KEYS + 8ull * NCAP;          // f32[NCAP]
constexpr size_t OFF_SY1   = OFF_SX1 + 4ull * NCAP;
constexpr size_t OFF_SX2   = OFF_SY1 + 4ull * NCAP;
constexpr size_t OFF_SY2   = OFF_SX2 + 4ull * NCAP;
constexpr size_t OFF_AREA  = OFF_SY2 + 4ull * NCAP;
constexpr size_t OFF_SORIG = OFF_AREA + 4ull * NCAP;          // u32[NCAP]
constexpr size_t OFF_KEEPS = OFF_SORIG + 4ull * NCAP;         // u32[NCAP]
constexpr size_t OFF_KORIG = OFF_KEEPS + 4ull * NCAP;         // u32[NCAP] (unused)
constexpr size_t OFF_TOPV  = OFF_KORIG + 4ull * NCAP;         // f32[1024]
constexpr size_t OFF_TOPI  = OFF_TOPV + 4096;                 // i32[1024]
constexpr size_t OFF_DIAG2 = OFF_TOPI + 4096;                 // u64[2*NCAP] = 128 KB, interleaved
constexpr size_t OFF_MASK  = OFF_DIAG2 + 16ull * NCAP;        // u64[NCAP*WROW] = 8 MB
constexpr size_t WS_NEED_MASK = OFF_MASK + 8ull * NCAP * WROW;
constexpr size_t OFF_CNZ   = WS_NEED_MASK;                    // u64[64*NBX] = 64 KB
constexpr size_t WS_NEED_NZ = OFF_CNZ + 8ull * 64 * NBX;

// Barrier that does NOT drain vmcnt: LDS-only wait + raw s_barrier.
__device__ __forceinline__ void barrier_nodrain() {
  asm volatile("s_waitcnt lgkmcnt(0)" ::: "memory");
  __builtin_amdgcn_s_barrier();
  asm volatile("" ::: "memory");
}

// ---- DPP full-wave OR reduce (R20/R21) ------------------------------------
template <int CTRL, int RMASK>
__device__ __forceinline__ unsigned or_dpp_step(unsigned x) {
  return x | (unsigned)__builtin_amdgcn_update_dpp(0, (int)x, CTRL, RMASK, 0xf, true);
}
__device__ __forceinline__ u64 wave_or64(u64 x) {
  unsigned lo = (unsigned)x, hi = (unsigned)(x >> 32);
  lo = or_dpp_step<0x111, 0xf>(lo); hi = or_dpp_step<0x111, 0xf>(hi);  // row_shr:1
  lo = or_dpp_step<0x112, 0xf>(lo); hi = or_dpp_step<0x112, 0xf>(hi);  // row_shr:2
  lo = or_dpp_step<0x114, 0xf>(lo); hi = or_dpp_step<0x114, 0xf>(hi);  // row_shr:4
  lo = or_dpp_step<0x118, 0xf>(lo); hi = or_dpp_step<0x118, 0xf>(hi);  // row_shr:8
  lo = or_dpp_step<0x142, 0xa>(lo); hi = or_dpp_step<0x142, 0xa>(hi);  // row_bcast:15
  lo = or_dpp_step<0x143, 0xc>(lo); hi = or_dpp_step<0x143, 0xc>(hi);  // row_bcast:31
  lo = (unsigned)__builtin_amdgcn_readlane((int)lo, 63);
  hi = (unsigned)__builtin_amdgcn_readlane((int)hi, 63);
  return ((u64)hi << 32) | lo;
}

// ---------------- bitonic building blocks (shared by k_psort / k_merge) ----
#define SS1(M)                                                              \
  { int tt = base + (M) * 64 + l;                                           \
    u64 a = e[M];                                                           \
    unsigned slo = __shfl_xor((unsigned)a, (int)jj);                        \
    unsigned shi = __shfl_xor((unsigned)(a >> 32), (int)jj);                \
    u64 b = ((u64)shi << 32) | slo;                                         \
    bool up = ((tt & bk) == 0);                                             \
    bool lowr = ((l & (int)jj) == 0);                                       \
    bool tmin = (up == lowr);                                               \
    bool agtb = (a > b);                                                    \
    e[M] = (tmin == agtb) ? b : a; }

#define SSTEP() { SS1(0) SS1(1) SS1(2) SS1(3) SS1(4) SS1(5) SS1(6) SS1(7) }

#define CSW(A, B)                                                           \
  { int tt = base + (A) * 64 + l;                                           \
    bool up = ((tt & bk) == 0);                                             \
    u64 xa = e[A], xb = e[B];                                               \
    bool sw = up ? (xa > xb) : (xa < xb);                                   \
    e[A] = sw ? xb : xa; e[B] = sw ? xa : xb; }

#define RSTEP4() { CSW(0,4) CSW(1,5) CSW(2,6) CSW(3,7) }
#define RSTEP2() { CSW(0,2) CSW(1,3) CSW(4,6) CSW(5,7) }
#define RSTEP1() { CSW(0,1) CSW(2,3) CSW(4,5) CSW(6,7) }

// ---------------------------------------------------------------------------
// Parallel pre-sort (16 blocks x 1 wave) + colNZ zeroing.
// ---------------------------------------------------------------------------
__global__ __launch_bounds__(64) void k_psort(
    const float* __restrict__ conf, int N, int C,
    u64* __restrict__ keys, u64* __restrict__ colnz) {
  const int l = threadIdx.x;
  const int base = blockIdx.x * 512;
  if (colnz) {   // zero the 64 KB summary (16*64 threads x 8 u64)
    size_t b = (size_t)(blockIdx.x * 64 + l) * 8;
#pragma unroll
    for (int i = 0; i < 8; ++i) colnz[b + i] = 0ull;
  }
  u64 e[8];
#pragma unroll
  for (int m = 0; m < 8; ++m) {
    int row = base + m * 64 + l;
    u64 key;
    if (row < N) {
      const float* cr = conf + (size_t)row * C;
      float mx = cr[0];
      for (int c = 1; c < C; ++c) mx = fmaxf(mx, cr[c]);
      unsigned int k32;
      if (mx > 0.6f) {
        union { float f; unsigned int u; } s; s.f = cr[0];
        unsigned int u = s.u;
        u = (u & 0x80000000u) ? ~u : (u | 0x80000000u);  // monotone map
        k32 = ~u;                                        // descending
        if (k32 == 0xFFFFFFFFu) k32 = 0xFFFFFFFEu;       // reserve invalid
      } else {
        k32 = 0xFFFFFFFFu;
      }
      key = ((u64)k32 << 32) | (unsigned int)row;
    } else {
      key = ((u64)0xFFFFFFFFu << 32);
    }
    e[m] = key;
  }
  for (unsigned bk = 2; bk <= 512; bk <<= 1) {
    unsigned j = bk >> 1;
    if (j == 256) { RSTEP4(); j = 128; }
    if (j == 128) { RSTEP2(); j = 64; }
    if (j == 64)  { RSTEP1(); j = 32; }
    for (unsigned jj = j; jj >= 1; jj >>= 1) SSTEP();
  }
#pragma unroll
  for (int m = 0; m < 8; ++m) keys[base + m * 64 + l] = e[m];
}

// ---------------------------------------------------------------------------
// Merge phases bk=1024..8192 (one block) + count/gather epilogue.
// ---------------------------------------------------------------------------
__global__ __launch_bounds__(1024) void k_merge(
    const float* __restrict__ loc,
    u64* __restrict__ keys, unsigned int* __restrict__ cnt,
    float* __restrict__ sx1, float* __restrict__ sy1,
    float* __restrict__ sx2, float* __restrict__ sy2,
    float* __restrict__ sarea, unsigned int* __restrict__ sorig) {
  __shared__ u64 sk[NCAP];  // 64 KiB (j>=512 sessions)
  __shared__ int wsum[16];
  const int tid = threadIdx.x;
  const int w = tid >> 6, l = tid & 63;
  const int base = w * 512;
  u64 e[8];
#pragma unroll
  for (int m = 0; m < 8; ++m) e[m] = keys[base + m * 64 + l];

  for (unsigned bk = 1024; bk <= NCAP; bk <<= 1) {
    unsigned j = bk >> 1;   // >= 512 always
    {
#pragma unroll
      for (int m = 0; m < 8; ++m) sk[base + m * 64 + l] = e[m];
      __syncthreads();
      for (unsigned j2 = bk >> 1; j2 >= 512; j2 >>= 1) {
        for (int tl = tid; tl < NCAP; tl += 1024) {
          unsigned p = (unsigned)tl ^ j2;
          if (p > (unsigned)tl) {
            bool up = ((tl & bk) == 0);
            u64 x = sk[tl], y = sk[p];
            bool sw = up ? (x > y) : (x < y);
            if (sw) { sk[tl] = y; sk[p] = x; }
          }
        }
        __syncthreads();
      }
#pragma unroll
      for (int m = 0; m < 8; ++m) e[m] = sk[base + m * 64 + l];
      __syncthreads();   // protect sk reads from next session's writes
      j = 256;
    }
    if (j == 256) { RSTEP4(); j = 128; }
    if (j == 128) { RSTEP2(); j = 64; }
    if (j == 64)  { RSTEP1(); j = 32; }
    for (unsigned jj = j; jj >= 1; jj >>= 1) SSTEP();
  }

  // epilogue: count valid + fused gather
  int cv = 0;
#pragma unroll
  for (int m = 0; m < 8; ++m) {
    int idx = base + m * 64 + l;
    u64 key = e[m];
    if ((key >> 32) != 0xFFFFFFFFull) ++cv;
    unsigned row = (unsigned)(key & 0xFFFFFFFFull);
    const float* b = loc + (size_t)row * 4;
    float x1 = b[0], y1 = b[1], x2 = b[2], y2 = b[3];
    sx1[idx] = x1; sy1[idx] = y1; sx2[idx] = x2; sy2[idx] = y2;
    sarea[idx] = (x2 - x1) * (y2 - y1);   // numpy op order, no FMA hazard
    sorig[idx] = row;
  }
  for (int off = 32; off; off >>= 1) cv += __shfl_down(cv, off);
  if (l == 0) wsum[w] = cv;
  __syncthreads();
  if (tid == 0) {
    int s = 0;
    for (int i = 0; i < 16; ++i) s += wsum[i];
    cnt[0] = (unsigned int)s;
  }
}

// Pairwise IoU>0.5 bitmask, 64x64 tiles, 1 wave per block.
// R22: also emit colNZ[pair][bx] |= ballot(word nonzero) — 1 atomic per
// nonzero tile (rare). cnz==nullptr disables.
__global__ __launch_bounds__(64) void k_mask(
    const float* __restrict__ sx1, const float* __restrict__ sy1,
    const float* __restrict__ sx2, const float* __restrict__ sy2,
    const float* __restrict__ sarea,
    u64* __restrict__ mask, u64* __restrict__ diagI,
    u64* __restrict__ cnz) {
  if (blockIdx.y < (blockIdx.x & ~1u)) return;
  __shared__ float jx1[64], jy1[64], jx2[64], jy2[64], ja[64];
  int t = threadIdx.x;
  int jbase = blockIdx.y * 64;
  jx1[t] = sx1[jbase + t]; jy1[t] = sy1[jbase + t];
  jx2[t] = sx2[jbase + t]; jy2[t] = sy2[jbase + t];
  ja[t]  = sarea[jbase + t];
  __syncthreads();
  int i = blockIdx.x * 64 + t;
  float xi1 = sx1[i], yi1 = sy1[i], xi2 = sx2[i], yi2 = sy2[i], ai = sarea[i];
  u64 bits = 0ULL;
#pragma unroll 8
  for (int jj = 0; jj < 64; ++jj) {
    float xx1 = fmaxf(xi1, jx1[jj]);
    float yy1 = fmaxf(yi1, jy1[jj]);
    float xx2 = fminf(xi2, jx2[jj]);
    float yy2 = fminf(yi2, jy2[jj]);
    float w = fmaxf(xx2 - xx1, 0.0f);
    float h = fmaxf(yy2 - yy1, 0.0f);
    float inter = w * h;
    float den = ai + ja[jj] - inter;   // (ai + aj) - inter, numpy order
    float iou = inter / den;           // IEEE div; 0/0 -> NaN -> compare false
    if (iou > 0.5f) bits |= (1ULL << jj);
  }
  mask[(size_t)i * WROW + blockIdx.y] = bits;
  if ((blockIdx.y >> 1) == (blockIdx.x >> 1))
    diagI[((size_t)i << 1) + (blockIdx.y & 1)] = bits;
  if (cnz != nullptr) {
    u64 nzb = __ballot(bits != 0ULL);   // bit t = (row bx*64+t)'s word-by nonzero
    if (t == 0 && nzb)
      atomicOr((unsigned long long*)&cnz[((size_t)(blockIdx.y >> 1)) * NBX + blockIdx.x], nzb);
  }
}

// ---------------------------------------------------------------------------
// Chunked greedy scan — R17 algorithm; R19 nodrain barriers; R21 DPP OR;
// R24 register-resident sparsity gate (1-deep self-prefetch, no LDS relay).
// USE_NZ=0 reproduces the R21 path exactly.
// ---------------------------------------------------------------------------
template <int USE_NZ>
__global__ __launch_bounds__(1024) void k_scan(
    const u64* __restrict__ mask,
    const u64* __restrict__ diagIg,
    const u64* __restrict__ cnzv,
    unsigned int* __restrict__ cnt,
    unsigned int* __restrict__ keeps) {
  __shared__ __align__(16) u64 ldsDiag[2 * NCAP];   // 128 KB, interleaved
  __shared__ __align__(16) u64 rem[WROW];           // removed-set (1 KB)
  __shared__ u64 ldsKA, ldsKB;
  __shared__ int ldsKb;
  const int tid = threadIdx.x;
  const int F = (int)cnt[0];
  const int nch = (F + 127) >> 7;
  const ulonglong2* __restrict__ m2 = (const ulonglong2*)mask;  // 64 pairs/row

  for (int i = tid; i < 2 * NCAP; i += 1024) ldsDiag[i] = diagIg[i];
  for (int w = tid; w < WROW; w += 1024) rem[w] = 0;

  const int p0 = tid & 63;    // pair index (words 2p0, 2p0+1) of held rows
  const int g0 = tid >> 6;    // row group: rows g0 + 16k (k<8) of each chunk
  int K = 0;

  // ---- register gate: cz[H] = (nzA, nzB) for this thread's pair p0 -------
  const ulonglong2* __restrict__ cz =
      (const ulonglong2*)cnzv + (size_t)p0 * (NBX / 2);
  ulonglong2 nzp = {0, 0};
  if (USE_NZ && nch > 0) nzp = cz[0];
  __syncthreads();            // staging + rem init visible (full drain ok, once)

  for (int H = 0; H < nch; ++H) {
    const size_t gb = (size_t)H * 8192;   // chunk = 8192 linear 16B units
    const int base = H << 7;
    const bool ld = (p0 > H);             // both words >= 2H+2
    // summary bits for this chunk (all-ones when disabled)
    u64 nzA = ~0ull, nzB = ~0ull;
    if (USE_NZ) { nzA = nzp.x; nzB = nzp.y; }
    ulonglong2 v0 = {0,0}, v1 = {0,0}, v2 = {0,0}, v3 = {0,0},
               v4 = {0,0}, v5 = {0,0}, v6 = {0,0}, v7 = {0,0};
    if (ld) {
      if ((nzA >> (g0 +  0)) & 1ull) v0 = m2[gb + tid];
      if ((nzA >> (g0 + 16)) & 1ull) v1 = m2[gb + tid + 1024];
      if ((nzA >> (g0 + 32)) & 1ull) v2 = m2[gb + tid + 2048];
      if ((nzA >> (g0 + 48)) & 1ull) v3 = m2[gb + tid + 3072];
      if ((nzB >> (g0 +  0)) & 1ull) v4 = m2[gb + tid + 4096];
      if ((nzB >> (g0 + 16)) & 1ull) v5 = m2[gb + tid + 5120];
      if ((nzB >> (g0 + 32)) & 1ull) v6 = m2[gb + tid + 6144];
      if ((nzB >> (g0 + 48)) & 1ull) v7 = m2[gb + tid + 7168];
    }
    // prefetch next chunk's gate (completes under the greedy below)
    ulonglong2 nzn = {0, 0};
    if (USE_NZ && H + 1 < nch) nzn = cz[H + 1];
    barrier_nodrain();   // prev chunk's rem ORs visible; loads stay in flight

    if (tid < 64) {
      // 3 LDS reads total: (DA,AB) b128, DB, (sup0,supB0) b128
      ulonglong2 dAB = *(const ulonglong2*)&ldsDiag[(size_t)(base + tid) << 1];
      u64 DA = dAB.x, AB = dAB.y;
      u64 DB = ldsDiag[(((size_t)(base + 64 + tid)) << 1) + 1];
      ulonglong2 supP = *(const ulonglong2*)&rem[2 * H];
      u64 sup0 = supP.x, supB0 = supP.y;

      int remrows = F - base;
      u64 validA = (remrows >= 64) ? ~0ull : ((1ull << remrows) - 1ull);
      int r2 = remrows - 64;
      u64 validB = (r2 >= 64) ? ~0ull : ((r2 <= 0) ? 0ull : ((1ull << r2) - 1ull));

      // ---- sub-greedy A (R10 involved-set shortcut) ----
      u64 DfwdA = (tid < 63) ? (DA & (~0ull << (tid + 1))) : 0ull;
      u64 undec = validA & ~sup0;
      u64 dmask = ((undec >> tid) & 1ull) ? DfwdA : 0ull;
      u64 vuln = wave_or64(dmask);
      u64 dang = __ballot(dmask != 0ull);
      u64 involved = (dang | vuln) & undec;
      u64 keepA = undec & ~involved;
      u64 und2 = involved;
      {
        unsigned Flo = (unsigned)DfwdA, Fhi = (unsigned)(DfwdA >> 32);
        while (und2) {
          int rr = __builtin_ctzll(und2);
          keepA |= 1ull << rr;
          unsigned dlo = __builtin_amdgcn_readlane(Flo, rr);
          unsigned dhi = __builtin_amdgcn_readlane(Fhi, rr);
          und2 &= ~((((u64)dhi << 32) | (u64)dlo) | (1ull << rr));
        }
      }

      // ---- A -> B suppression, then sub-greedy B ----
      u64 abm = ((keepA >> tid) & 1ull) ? AB : 0ull;
      u64 supB = supB0 | wave_or64(abm);
      u64 DfwdB = (tid < 63) ? (DB & (~0ull << (tid + 1))) : 0ull;
      u64 undecB = validB & ~supB;
      u64 dmaskB = ((undecB >> tid) & 1ull) ? DfwdB : 0ull;
      u64 vulnB = wave_or64(dmaskB);
      u64 dangB = __ballot(dmaskB != 0ull);
      u64 involvedB = (dangB | vulnB) & undecB;
      u64 keepB = undecB & ~involvedB;
      u64 und2B = involvedB;
      {
        unsigned Flo = (unsigned)DfwdB, Fhi = (unsigned)(DfwdB >> 32);
        while (und2B) {
          int rr = __builtin_ctzll(und2B);
          keepB |= 1ull << rr;
          unsigned dlo = __builtin_amdgcn_readlane(Flo, rr);
          unsigned dhi = __builtin_amdgcn_readlane(Fhi, rr);
          und2B &= ~((((u64)dhi << 32) | (u64)dlo) | (1ull << rr));
        }
      }

      if (tid == 0) { ldsKA = keepA; ldsKB = keepB; ldsKb = K; }
      K += __popcll(keepA) + __popcll(keepB);   // uniform; stores by wave 1
    }
    barrier_nodrain();   // ldsKA/ldsKB/ldsKb visible; loads still in flight

    const u64 keepA = ldsKA, keepB = ldsKB;

    // ---- keeps store by WAVE 1 (off wave-0's serial segment) ----
    if (g0 == 1) {
      const int l = p0;
      const int Kb = ldsKb;
      int pcA = __popcll(keepA);
      unsigned kloA = (unsigned)keepA, khiA = (unsigned)(keepA >> 32);
      int preA = __builtin_amdgcn_mbcnt_hi(khiA, __builtin_amdgcn_mbcnt_lo(kloA, 0));
      if ((keepA >> l) & 1ull) keeps[Kb + preA] = (unsigned)(base + l);
      unsigned kloB = (unsigned)keepB, khiB = (unsigned)(keepB >> 32);
      int preB = __builtin_amdgcn_mbcnt_hi(khiB, __builtin_amdgcn_mbcnt_lo(kloB, 0));
      if ((keepB >> l) & 1ull) keeps[Kb + pcA + preB] = (unsigned)(base + 64 + l);
    }

    if (ld && (keepA | keepB)) {
      u64 ax = 0, ay = 0;                  // register pre-OR (R14)
      if ((keepA >> g0) & 1ull)        { ax |= v0.x; ay |= v0.y; }
      if ((keepA >> (g0+16)) & 1ull)   { ax |= v1.x; ay |= v1.y; }
      if ((keepA >> (g0+32)) & 1ull)   { ax |= v2.x; ay |= v2.y; }
      if ((keepA >> (g0+48)) & 1ull)   { ax |= v3.x; ay |= v3.y; }
      if ((keepB >> g0) & 1ull)        { ax |= v4.x; ay |= v4.y; }
      if ((keepB >> (g0+16)) & 1ull)   { ax |= v5.x; ay |= v5.y; }
      if ((keepB >> (g0+32)) & 1ull)   { ax |= v6.x; ay |= v6.y; }
      if ((keepB >> (g0+48)) & 1ull)   { ax |= v7.x; ay |= v7.y; }
      const int w0 = 2 * p0;
      if (ax) atomicOr(&rem[w0], ax);
      if (ay) atomicOr(&rem[w0 + 1], ay);
    }
    nzp = nzn;   // advance register gate
    // next iteration's barrier_nodrain (lgkmcnt(0)) orders these ORs
    // before the rem reads
  }
  if (tid == 0) cnt[1] = (unsigned int)K;
}

// Fallback (small workspace): on-the-fly IoU greedy scan in one block.
__global__ __launch_bounds__(256) void k_scan_nomask(
    const float* __restrict__ sx1, const float* __restrict__ sy1,
    const float* __restrict__ sx2, const float* __restrict__ sy2,
    const float* __restrict__ sarea,
    unsigned int* __restrict__ cnt,
    unsigned int* __restrict__ keeps) {
  __shared__ unsigned char sup[NCAP];
  __shared__ int sK;
  int tid = threadIdx.x;
  int F = (int)cnt[0];
  for (int j = tid; j < NCAP; j += 256) sup[j] = 0;
  if (tid == 0) sK = 0;
  __syncthreads();
  for (int i = 0; i < F; ++i) {
    if (!sup[i]) {
      if (tid == 0) keeps[sK++] = (unsigned int)i;
      float xi1 = sx1[i], yi1 = sy1[i], xi2 = sx2[i], yi2 = sy2[i], ai = sarea[i];
      for (int j = i + 1 + tid; j < F; j += 256) {
        if (sup[j]) continue;
        float xx1 = fmaxf(xi1, sx1[j]);
        float yy1 = fmaxf(yi1, sy1[j]);
        float xx2 = fminf(xi2, sx2[j]);
        float yy2 = fminf(yi2, sy2[j]);
        float w = fmaxf(xx2 - xx1, 0.0f);
        float h = fmaxf(yy2 - yy1, 0.0f);
        float inter = w * h;
        float iou = inter / (ai + sarea[j] - inter);
        if (iou > 0.5f) sup[j] = 1;
      }
    }
    __syncthreads();
  }
  if (tid == 0) cnt[1] = (unsigned int)sK;
}

// ---------------------------------------------------------------------------
// Per class: top-KT over M kept boxes, REGISTER-RESIDENT (R13, unchanged).
// ---------------------------------------------------------------------------
__global__ __launch_bounds__(1024) void k_topk(
    const float* __restrict__ conf,
    const unsigned int* __restrict__ sorig,
    const unsigned int* __restrict__ keeps,
    const unsigned int* __restrict__ cnt,
    int C, int KT,
    float* __restrict__ topv, int* __restrict__ topi) {
  __shared__ float wlv[16];
  __shared__ int wli[16];
  __shared__ float ldsWv;
  __shared__ int ldsWj;
  const int tid = threadIdx.x;
  const int lane = tid & 63;
  const int wv_ = tid >> 6;
  const int c = blockIdx.x;
  const int M = (int)cnt[1];

  const float NEG = -3.402823466e+38f;
  float v[8];
#pragma unroll
  for (int k = 0; k < 8; ++k) {
    int j = tid + (k << 10);
    v[k] = (j < M) ? conf[(size_t)sorig[keeps[j]] * C + c] : NEG;
  }
  float bv = NEG; int bk_ = -1;
#pragma unroll
  for (int k = 0; k < 8; ++k)
    if (v[k] > bv) { bv = v[k]; bk_ = k; }
  int bj = (bk_ >= 0) ? (tid + (bk_ << 10)) : 0x7FFFFFFF;
  if (bv == NEG) bj = 0x7FFFFFFF;

  for (int t = 0; t < KT; ++t) {
    float rv = bv; int rj = bj;
#pragma unroll
    for (int off = 32; off; off >>= 1) {
      float v2 = __shfl_down(rv, off);
      int   j2 = __shfl_down(rj, off);
      if (v2 > rv || (v2 == rv && j2 < rj)) { rv = v2; rj = j2; }
    }
    if (lane == 0) { wlv[wv_] = rv; wli[wv_] = rj; }
    __syncthreads();
    if (wv_ == 0) {
      float fv = (lane < 16) ? wlv[lane] : NEG;
      int   fj = (lane < 16) ? wli[lane] : 0x7FFFFFFF;
#pragma unroll
      for (int off = 32; off; off >>= 1) {
        float v2 = __shfl_down(fv, off);
        int   j2 = __shfl_down(fj, off);
        if (v2 > fv || (v2 == fv && j2 < fj)) { fv = v2; fj = j2; }
      }
      if (lane == 0) {
        ldsWv = fv; ldsWj = fj;
        topv[c * KT + t] = fv;
        topi[c * KT + t] = (fj == 0x7FFFFFFF) ? 0 : fj;  // M<KT safety
      }
    }
    __syncthreads();
    const int wj = ldsWj;
    if (wj != 0x7FFFFFFF && (wj & 1023) == tid) {
      int kk = wj >> 10;
#pragma unroll
      for (int k = 0; k < 8; ++k)
        if (k == kk) v[k] = NEG;
      bv = NEG; bk_ = -1;
#pragma unroll
      for (int k = 0; k < 8; ++k)
        if (v[k] > bv) { bv = v[k]; bk_ = k; }
      bj = (bk_ >= 0) ? (tid + (bk_ << 10)) : 0x7FFFFFFF;
      if (bv == NEG) bj = 0x7FFFFFFF;
    }
  }
}

// Final scalar: smooth-L1 over (KT, C, 4) gathered boxes + focal CE on
// (class0 top-KT > 0.5), divided by M.
__global__ __launch_bounds__(256) void k_loss(
    const float* __restrict__ loc, const float* __restrict__ tb,
    const int* __restrict__ labels,
    const unsigned int* __restrict__ sorig,
    const unsigned int* __restrict__ keeps,
    const float* __restrict__ topv, const int* __restrict__ topi,
    const unsigned int* __restrict__ cnt, int C, int KT,
    float* __restrict__ out) {
  __shared__ float red[256];
  int tid = threadIdx.x;
  int F = (int)cnt[0];
  int M = (int)cnt[1];
  if (F == 0 || M == 0) {
    if (tid == 0) out[0] = 0.001f;
    return;
  }
  int total = KT * C * 4;
  float part = 0.0f;
  for (int e = tid; e < total; e += 256) {
    int d = e & 3;
    int q = e >> 2;
    int c = q % C;
    int i = q / C;
    int j = topi[c * KT + i];
    unsigned int orow = sorig[keeps[j]];
    float pred = loc[(size_t)orow * 4 + d];
    float tg = tb[c * 4 + d];
    float dd = fabsf(pred - tg);
    part += (dd < 1.0f) ? (0.5f * dd * dd) : (dd - 0.5f);
  }
  red[tid] = part;
  __syncthreads();
  for (int s = 128; s > 0; s >>= 1) {
    if (tid < s) red[tid] += red[tid + s];
    __syncthreads();
  }
  if (tid == 0) {
    float loc_loss = red[0];
    float mx = -3.402823466e+38f;
    for (int i = 0; i < KT; ++i) {
      float x = (topv[i] > 0.5f) ? 1.0f : 0.0f;   // class 0 column
      mx = fmaxf(mx, x);
    }
    float ssum = 0.0f;
    for (int i = 0; i < KT; ++i) {
      float x = (topv[i] > 0.5f) ? 1.0f : 0.0f;
      ssum += expf(x - mx);
    }
    float lse = mx + logf(ssum);
    float ce = 0.0f;
    for (int i = 0; i < KT; ++i) {
      float x = (topv[i] > 0.5f) ? 1.0f : 0.0f;
      ce += (float)labels[i] * (x - lse);
    }
    ce = -ce;
    float pt = expf(-ce);
    float om = 1.0f - pt;
    float conf_loss = 0.25f * om * om * ce;   // ALPHA=0.25, GAMMA=2
    out[0] = (loc_loss + conf_loss) / (float)M;
  }
}

// ---------------- host ------------------------------------------------------

extern "C" void kernel_launch(void* const* d_in, const int* in_sizes, int n_in,
                              void* d_out, int out_size, void* d_ws, size_t ws_size,
                              hipStream_t stream) {
  (void)n_in; (void)out_size;
  const float* loc    = (const float*)d_in[0];
  const float* conf   = (const float*)d_in[1];
  const float* tb     = (const float*)d_in[2];
  const int*   labels = (const int*)d_in[3];
  float* out = (float*)d_out;

  int N = in_sizes[0] / 4;
  if (N > NCAP) N = NCAP;
  int C  = (N > 0) ? (in_sizes[1] / N) : 20;
  int KT = in_sizes[3];

  char* ws = (char*)d_ws;
  unsigned int* cnt   = (unsigned int*)(ws + OFF_CNT);
  u64*          keys  = (u64*)(ws + OFF_KEYS);
  float*        sx1   = (float*)(ws + OFF_SX1);
  float*        sy1   = (float*)(ws + OFF_SY1);
  float*        sx2   = (float*)(ws + OFF_SX2);
  float*        sy2   = (float*)(ws + OFF_SY2);
  float*        sarea = (float*)(ws + OFF_AREA);
  unsigned int* sorig = (unsigned int*)(ws + OFF_SORIG);
  unsigned int* keeps = (unsigned int*)(ws + OFF_KEEPS);
  float*        topv  = (float*)(ws + OFF_TOPV);
  int*          topi  = (int*)(ws + OFF_TOPI);
  u64*          diagI = (u64*)(ws + OFF_DIAG2);
  u64*          mask  = (u64*)(ws + OFF_MASK);
  u64*          colnz = (u64*)(ws + OFF_CNZ);

  bool use_mask = (ws_size >= WS_NEED_MASK);
  bool use_nz   = (ws_size >= WS_NEED_NZ);

  k_psort<<<16, 64, 0, stream>>>(conf, N, C, keys, use_nz ? colnz : nullptr);
  k_merge<<<1, 1024, 0, stream>>>(loc, keys, cnt,
                                  sx1, sy1, sx2, sy2, sarea, sorig);
  if (use_mask) {
    k_mask<<<dim3(WROW, WROW), 64, 0, stream>>>(sx1, sy1, sx2, sy2, sarea,
                                                mask, diagI,
                                                use_nz ? colnz : nullptr);
    if (use_nz)
      k_scan<1><<<1, 1024, 0, stream>>>(mask, diagI, colnz, cnt, keeps);
    else
      k_scan<0><<<1, 1024, 0, stream>>>(mask, diagI, colnz, cnt, keeps);
  } else {
    k_scan_nomask<<<1, 256, 0, stream>>>(sx1, sy1, sx2, sy2, sarea, cnt, keeps);
  }
  k_topk<<<C, 1024, 0, stream>>>(conf, sorig, keeps, cnt, C, KT, topv, topi);
  k_loss<<<1, 256, 0, stream>>>(loc, tb, labels, sorig, keeps, topv, topi, cnt, C, KT, out);
}

// Round 7
// 307.778 us; speedup vs baseline: 1.0357x; 1.0357x over previous
//
#include <hip/hip_runtime.h>
#include <stdint.h>
#include <stddef.h>

// ---------------------------------------------------------------------------
// BoundingBox loss processor:
//   filter (maxconf > 0.6) -> sort by class-0 score desc (stable, idx asc)
//   -> greedy NMS (IoU > 0.5 suppress) -> per-class top-20 over kept
//   -> smooth-L1 sum + focal CE on (class0 top-20 > 0.5) -> /M
//
// Journal: R10 involved-set greedy. R13 register topk. R14 pre-OR atomics.
// R15 128-row chunks. R17 short wave-0 segment. R18 sort split.
// R19 NULL: no-drain barriers — loads already hidden.
// R20/R21 WIN: DPP wave-OR (ds_bpermute -> VALU DPP), 137->99.8us.
// R24: sparsity gate — FETCH 2308->374KB but dur 99.8->115us. k_scan is NOT
// BW-bound (24GB/s was demand, not limit); gate's per-lane exec-mask
// overhead (+580cy/chunk) hurt. Bytes are free -> drop the gate.
// R25: REDUNDANT GREEDY + SINGLE BARRIER. The greedy's inputs (ldsDiag row,
// rem[2H], valid masks) are identical in every wave -> every wave computes
// keepA/keepB/K redundantly (bit-identical, lane-uniform). Removes barrier
// B2 + the ldsKA/ldsKB/ldsKb LDS publish; 15-waves-idle-during-greedy
// becomes 4-way SMT-overlapped compute; consume + next-issue flow
// barrier-free into the next B1 (nodrain: lgkmcnt(0)+s_barrier orders the
// rem atomicOrs; v-reg vmcnt waits are compiler-inserted at consume).
// ---------------------------------------------------------------------------

#define NCAP 8192
#define WROW (NCAP / 64)   // 128 u64 words per mask row

typedef unsigned long long u64;

// ---------------- workspace layout (all offsets 16-byte aligned) -----------
constexpr size_t OFF_CNT   = 0;                               // 2 x u32: [0]=F, [1]=M
constexpr size_t OFF_KEYS  = 256;                             // u64[NCAP] (psort->merge)
constexpr size_t OFF_SX1   = OFF_KEYS + 8ull * NCAP;          // f32[NCAP]
constexpr size_t OFF_SY1   = OFF_SX1 + 4ull * NCAP;
constexpr size_t OFF_SX2   = OFF_SY1 + 4ull * NCAP;
constexpr size_t OFF_SY2   = OFF_SX2 + 4ull * NCAP;
constexpr size_t OFF_AREA  = OFF_SY2 + 4ull * NCAP;
constexpr size_t OFF_SORIG = OFF_AREA + 4ull * NCAP;          // u32[NCAP]
constexpr size_t OFF_KEEPS = OFF_SORIG + 4ull * NCAP;         // u32[NCAP]
constexpr size_t OFF_KORIG = OFF_KEEPS + 4ull * NCAP;         // u32[NCAP] (unused)
constexpr size_t OFF_TOPV  = OFF_KORIG + 4ull * NCAP;         // f32[1024]
constexpr size_t OFF_TOPI  = OFF_TOPV + 4096;                 // i32[1024]
constexpr size_t OFF_DIAG2 = OFF_TOPI + 4096;                 // u64[2*NCAP] = 128 KB, interleaved
constexpr size_t OFF_MASK  = OFF_DIAG2 + 16ull * NCAP;        // u64[NCAP*WROW] = 8 MB
constexpr size_t WS_NEED_MASK = OFF_MASK + 8ull * NCAP * WROW;

// Barrier that does NOT drain vmcnt: LDS-only wait + raw s_barrier.
__device__ __forceinline__ void barrier_nodrain() {
  asm volatile("s_waitcnt lgkmcnt(0)" ::: "memory");
  __builtin_amdgcn_s_barrier();
  asm volatile("" ::: "memory");
}

// ---- DPP full-wave OR reduce (R20/R21) ------------------------------------
template <int CTRL, int RMASK>
__device__ __forceinline__ unsigned or_dpp_step(unsigned x) {
  return x | (unsigned)__builtin_amdgcn_update_dpp(0, (int)x, CTRL, RMASK, 0xf, true);
}
__device__ __forceinline__ u64 wave_or64(u64 x) {
  unsigned lo = (unsigned)x, hi = (unsigned)(x >> 32);
  lo = or_dpp_step<0x111, 0xf>(lo); hi = or_dpp_step<0x111, 0xf>(hi);  // row_shr:1
  lo = or_dpp_step<0x112, 0xf>(lo); hi = or_dpp_step<0x112, 0xf>(hi);  // row_shr:2
  lo = or_dpp_step<0x114, 0xf>(lo); hi = or_dpp_step<0x114, 0xf>(hi);  // row_shr:4
  lo = or_dpp_step<0x118, 0xf>(lo); hi = or_dpp_step<0x118, 0xf>(hi);  // row_shr:8
  lo = or_dpp_step<0x142, 0xa>(lo); hi = or_dpp_step<0x142, 0xa>(hi);  // row_bcast:15
  lo = or_dpp_step<0x143, 0xc>(lo); hi = or_dpp_step<0x143, 0xc>(hi);  // row_bcast:31
  lo = (unsigned)__builtin_amdgcn_readlane((int)lo, 63);
  hi = (unsigned)__builtin_amdgcn_readlane((int)hi, 63);
  return ((u64)hi << 32) | lo;
}

// ---------------- bitonic building blocks (shared by k_psort / k_merge) ----
#define SS1(M)                                                              \
  { int tt = base + (M) * 64 + l;                                           \
    u64 a = e[M];                                                           \
    unsigned slo = __shfl_xor((unsigned)a, (int)jj);                        \
    unsigned shi = __shfl_xor((unsigned)(a >> 32), (int)jj);                \
    u64 b = ((u64)shi << 32) | slo;                                         \
    bool up = ((tt & bk) == 0);                                             \
    bool lowr = ((l & (int)jj) == 0);                                       \
    bool tmin = (up == lowr);                                               \
    bool agtb = (a > b);                                                    \
    e[M] = (tmin == agtb) ? b : a; }

#define SSTEP() { SS1(0) SS1(1) SS1(2) SS1(3) SS1(4) SS1(5) SS1(6) SS1(7) }

#define CSW(A, B)                                                           \
  { int tt = base + (A) * 64 + l;                                           \
    bool up = ((tt & bk) == 0);                                             \
    u64 xa = e[A], xb = e[B];                                               \
    bool sw = up ? (xa > xb) : (xa < xb);                                   \
    e[A] = sw ? xb : xa; e[B] = sw ? xa : xb; }

#define RSTEP4() { CSW(0,4) CSW(1,5) CSW(2,6) CSW(3,7) }
#define RSTEP2() { CSW(0,2) CSW(1,3) CSW(4,6) CSW(5,7) }
#define RSTEP1() { CSW(0,1) CSW(2,3) CSW(4,5) CSW(6,7) }

// ---------------------------------------------------------------------------
// Parallel pre-sort: 16 blocks x 1 wave; block b builds keys for rows
// [512b, 512b+512) and runs bitonic phases bk=2..512.
// ---------------------------------------------------------------------------
__global__ __launch_bounds__(64) void k_psort(
    const float* __restrict__ conf, int N, int C,
    u64* __restrict__ keys) {
  const int l = threadIdx.x;
  const int base = blockIdx.x * 512;
  u64 e[8];
#pragma unroll
  for (int m = 0; m < 8; ++m) {
    int row = base + m * 64 + l;
    u64 key;
    if (row < N) {
      const float* cr = conf + (size_t)row * C;
      float mx = cr[0];
      for (int c = 1; c < C; ++c) mx = fmaxf(mx, cr[c]);
      unsigned int k32;
      if (mx > 0.6f) {
        union { float f; unsigned int u; } s; s.f = cr[0];
        unsigned int u = s.u;
        u = (u & 0x80000000u) ? ~u : (u | 0x80000000u);  // monotone map
        k32 = ~u;                                        // descending
        if (k32 == 0xFFFFFFFFu) k32 = 0xFFFFFFFEu;       // reserve invalid
      } else {
        k32 = 0xFFFFFFFFu;
      }
      key = ((u64)k32 << 32) | (unsigned int)row;
    } else {
      key = ((u64)0xFFFFFFFFu << 32);
    }
    e[m] = key;
  }
  for (unsigned bk = 2; bk <= 512; bk <<= 1) {
    unsigned j = bk >> 1;
    if (j == 256) { RSTEP4(); j = 128; }
    if (j == 128) { RSTEP2(); j = 64; }
    if (j == 64)  { RSTEP1(); j = 32; }
    for (unsigned jj = j; jj >= 1; jj >>= 1) SSTEP();
  }
#pragma unroll
  for (int m = 0; m < 8; ++m) keys[base + m * 64 + l] = e[m];
}

// ---------------------------------------------------------------------------
// Merge phases bk=1024..8192 (one block) + count/gather epilogue.
// ---------------------------------------------------------------------------
__global__ __launch_bounds__(1024) void k_merge(
    const float* __restrict__ loc,
    u64* __restrict__ keys, unsigned int* __restrict__ cnt,
    float* __restrict__ sx1, float* __restrict__ sy1,
    float* __restrict__ sx2, float* __restrict__ sy2,
    float* __restrict__ sarea, unsigned int* __restrict__ sorig) {
  __shared__ u64 sk[NCAP];  // 64 KiB (j>=512 sessions)
  __shared__ int wsum[16];
  const int tid = threadIdx.x;
  const int w = tid >> 6, l = tid & 63;
  const int base = w * 512;
  u64 e[8];
#pragma unroll
  for (int m = 0; m < 8; ++m) e[m] = keys[base + m * 64 + l];

  for (unsigned bk = 1024; bk <= NCAP; bk <<= 1) {
    unsigned j = bk >> 1;   // >= 512 always
    {
#pragma unroll
      for (int m = 0; m < 8; ++m) sk[base + m * 64 + l] = e[m];
      __syncthreads();
      for (unsigned j2 = bk >> 1; j2 >= 512; j2 >>= 1) {
        for (int tl = tid; tl < NCAP; tl += 1024) {
          unsigned p = (unsigned)tl ^ j2;
          if (p > (unsigned)tl) {
            bool up = ((tl & bk) == 0);
            u64 x = sk[tl], y = sk[p];
            bool sw = up ? (x > y) : (x < y);
            if (sw) { sk[tl] = y; sk[p] = x; }
          }
        }
        __syncthreads();
      }
#pragma unroll
      for (int m = 0; m < 8; ++m) e[m] = sk[base + m * 64 + l];
      __syncthreads();   // protect sk reads from next session's writes
      j = 256;
    }
    if (j == 256) { RSTEP4(); j = 128; }
    if (j == 128) { RSTEP2(); j = 64; }
    if (j == 64)  { RSTEP1(); j = 32; }
    for (unsigned jj = j; jj >= 1; jj >>= 1) SSTEP();
  }

  // epilogue: count valid + fused gather
  int cv = 0;
#pragma unroll
  for (int m = 0; m < 8; ++m) {
    int idx = base + m * 64 + l;
    u64 key = e[m];
    if ((key >> 32) != 0xFFFFFFFFull) ++cv;
    unsigned row = (unsigned)(key & 0xFFFFFFFFull);
    const float* b = loc + (size_t)row * 4;
    float x1 = b[0], y1 = b[1], x2 = b[2], y2 = b[3];
    sx1[idx] = x1; sy1[idx] = y1; sx2[idx] = x2; sy2[idx] = y2;
    sarea[idx] = (x2 - x1) * (y2 - y1);   // numpy op order, no FMA hazard
    sorig[idx] = row;
  }
  for (int off = 32; off; off >>= 1) cv += __shfl_down(cv, off);
  if (l == 0) wsum[w] = cv;
  __syncthreads();
  if (tid == 0) {
    int s = 0;
    for (int i = 0; i < 16; ++i) s += wsum[i];
    cnt[0] = (unsigned int)s;
  }
}

// Pairwise IoU>0.5 bitmask, 64x64 tiles, 1 wave per block.
// Skip by < (bx & ~1) (never consumed). Diagonal-super blocks write the
// INTERLEAVED diag strip: diagI[2*i + (by&1)].
__global__ __launch_bounds__(64) void k_mask(
    const float* __restrict__ sx1, const float* __restrict__ sy1,
    const float* __restrict__ sx2, const float* __restrict__ sy2,
    const float* __restrict__ sarea,
    u64* __restrict__ mask, u64* __restrict__ diagI) {
  if (blockIdx.y < (blockIdx.x & ~1u)) return;
  __shared__ float jx1[64], jy1[64], jx2[64], jy2[64], ja[64];
  int t = threadIdx.x;
  int jbase = blockIdx.y * 64;
  jx1[t] = sx1[jbase + t]; jy1[t] = sy1[jbase + t];
  jx2[t] = sx2[jbase + t]; jy2[t] = sy2[jbase + t];
  ja[t]  = sarea[jbase + t];
  __syncthreads();
  int i = blockIdx.x * 64 + t;
  float xi1 = sx1[i], yi1 = sy1[i], xi2 = sx2[i], yi2 = sy2[i], ai = sarea[i];
  u64 bits = 0ULL;
#pragma unroll 8
  for (int jj = 0; jj < 64; ++jj) {
    float xx1 = fmaxf(xi1, jx1[jj]);
    float yy1 = fmaxf(yi1, jy1[jj]);
    float xx2 = fminf(xi2, jx2[jj]);
    float yy2 = fminf(yi2, jy2[jj]);
    float w = fmaxf(xx2 - xx1, 0.0f);
    float h = fmaxf(yy2 - yy1, 0.0f);
    float inter = w * h;
    float den = ai + ja[jj] - inter;   // (ai + aj) - inter, numpy order
    float iou = inter / den;           // IEEE div; 0/0 -> NaN -> compare false
    if (iou > 0.5f) bits |= (1ULL << jj);
  }
  mask[(size_t)i * WROW + blockIdx.y] = bits;
  if ((blockIdx.y >> 1) == (blockIdx.x >> 1))
    diagI[((size_t)i << 1) + (blockIdx.y & 1)] = bits;
}

// ---------------------------------------------------------------------------
// Chunked greedy scan — R25: redundant per-wave greedy, ONE nodrain barrier
// per chunk. Greedy inputs are wave-invariant -> keepA/keepB/K identical in
// every wave (lane-uniform); no ldsK publish, no second barrier. Loads are
// unconditional (R24 showed gating costs more than the bytes).
// ---------------------------------------------------------------------------
__global__ __launch_bounds__(1024) void k_scan(
    const u64* __restrict__ mask,
    const u64* __restrict__ diagIg,
    unsigned int* __restrict__ cnt,
    unsigned int* __restrict__ keeps) {
  __shared__ __align__(16) u64 ldsDiag[2 * NCAP];   // 128 KB, interleaved
  __shared__ __align__(16) u64 rem[WROW];           // removed-set (1 KB)
  const int tid = threadIdx.x;
  const int F = (int)cnt[0];
  const int nch = (F + 127) >> 7;
  const ulonglong2* __restrict__ m2 = (const ulonglong2*)mask;  // 64 pairs/row

  for (int i = tid; i < 2 * NCAP; i += 1024) ldsDiag[i] = diagIg[i];
  for (int w = tid; w < WROW; w += 1024) rem[w] = 0;

  const int p0 = tid & 63;    // pair index (words 2p0, 2p0+1) of held rows
  const int g0 = tid >> 6;    // row group: rows g0 + 16k (k<8) of each chunk
  const int l  = p0;          // lane index (greedy row-within-block index)
  int K = 0;
  __syncthreads();            // staging + rem init visible (full drain ok, once)

  for (int H = 0; H < nch; ++H) {
    const size_t gb = (size_t)H * 8192;   // chunk = 8192 linear 16B units
    const int base = H << 7;
    const bool ld = (p0 > H);             // both words >= 2H+2
    ulonglong2 v0 = {0,0}, v1 = {0,0}, v2 = {0,0}, v3 = {0,0},
               v4 = {0,0}, v5 = {0,0}, v6 = {0,0}, v7 = {0,0};
    if (ld) {
      v0 = m2[gb + tid];
      v1 = m2[gb + tid + 1024];
      v2 = m2[gb + tid + 2048];
      v3 = m2[gb + tid + 3072];
      v4 = m2[gb + tid + 4096];
      v5 = m2[gb + tid + 5120];
      v6 = m2[gb + tid + 6144];
      v7 = m2[gb + tid + 7168];
    }
    barrier_nodrain();   // prev chunk's rem ORs visible; loads stay in flight

    // ---- redundant greedy: EVERY wave computes identical keepA/keepB ----
    // 3 LDS reads: (DA,AB) b128, DB, (sup0,supB0) b128 — same addrs per lane
    ulonglong2 dAB = *(const ulonglong2*)&ldsDiag[(size_t)(base + l) << 1];
    u64 DA = dAB.x, AB = dAB.y;
    u64 DB = ldsDiag[(((size_t)(base + 64 + l)) << 1) + 1];
    ulonglong2 supP = *(const ulonglong2*)&rem[2 * H];
    u64 sup0 = supP.x, supB0 = supP.y;

    int remrows = F - base;
    u64 validA = (remrows >= 64) ? ~0ull : ((1ull << remrows) - 1ull);
    int r2 = remrows - 64;
    u64 validB = (r2 >= 64) ? ~0ull : ((r2 <= 0) ? 0ull : ((1ull << r2) - 1ull));

    // ---- sub-greedy A (R10 involved-set shortcut) ----
    u64 DfwdA = (l < 63) ? (DA & (~0ull << (l + 1))) : 0ull;
    u64 undec = validA & ~sup0;
    u64 dmask = ((undec >> l) & 1ull) ? DfwdA : 0ull;
    u64 vuln = wave_or64(dmask);
    u64 dang = __ballot(dmask != 0ull);
    u64 involved = (dang | vuln) & undec;
    u64 keepA = undec & ~involved;
    u64 und2 = involved;
    {
      unsigned Flo = (unsigned)DfwdA, Fhi = (unsigned)(DfwdA >> 32);
      while (und2) {
        int rr = __builtin_ctzll(und2);
        keepA |= 1ull << rr;
        unsigned dlo = __builtin_amdgcn_readlane(Flo, rr);
        unsigned dhi = __builtin_amdgcn_readlane(Fhi, rr);
        und2 &= ~((((u64)dhi << 32) | (u64)dlo) | (1ull << rr));
      }
    }

    // ---- A -> B suppression, then sub-greedy B ----
    u64 abm = ((keepA >> l) & 1ull) ? AB : 0ull;
    u64 supB = supB0 | wave_or64(abm);
    u64 DfwdB = (l < 63) ? (DB & (~0ull << (l + 1))) : 0ull;
    u64 undecB = validB & ~supB;
    u64 dmaskB = ((undecB >> l) & 1ull) ? DfwdB : 0ull;
    u64 vulnB = wave_or64(dmaskB);
    u64 dangB = __ballot(dmaskB != 0ull);
    u64 involvedB = (dangB | vulnB) & undecB;
    u64 keepB = undecB & ~involvedB;
    u64 und2B = involvedB;
    {
      unsigned Flo = (unsigned)DfwdB, Fhi = (unsigned)(DfwdB >> 32);
      while (und2B) {
        int rr = __builtin_ctzll(und2B);
        keepB |= 1ull << rr;
        unsigned dlo = __builtin_amdgcn_readlane(Flo, rr);
        unsigned dhi = __builtin_amdgcn_readlane(Fhi, rr);
        und2B &= ~((((u64)dhi << 32) | (u64)dlo) | (1ull << rr));
      }
    }

    const int Kb = K;                         // base BEFORE this chunk
    K += __popcll(keepA) + __popcll(keepB);   // identical in every wave

    // ---- keeps store by WAVE 1 (uses its own redundant keepA/keepB/Kb) ----
    if (g0 == 1) {
      int pcA = __popcll(keepA);
      unsigned kloA = (unsigned)keepA, khiA = (unsigned)(keepA >> 32);
      int preA = __builtin_amdgcn_mbcnt_hi(khiA, __builtin_amdgcn_mbcnt_lo(kloA, 0));
      if ((keepA >> l) & 1ull) keeps[Kb + preA] = (unsigned)(base + l);
      unsigned kloB = (unsigned)keepB, khiB = (unsigned)(keepB >> 32);
      int preB = __builtin_amdgcn_mbcnt_hi(khiB, __builtin_amdgcn_mbcnt_lo(kloB, 0));
      if ((keepB >> l) & 1ull) keeps[Kb + pcA + preB] = (unsigned)(base + 64 + l);
    }

    // ---- consume: register pre-OR (R14) + LDS atomicOr into rem ----
    if (ld && (keepA | keepB)) {
      u64 ax = 0, ay = 0;
      if ((keepA >> g0) & 1ull)        { ax |= v0.x; ay |= v0.y; }
      if ((keepA >> (g0+16)) & 1ull)   { ax |= v1.x; ay |= v1.y; }
      if ((keepA >> (g0+32)) & 1ull)   { ax |= v2.x; ay |= v2.y; }
      if ((keepA >> (g0+48)) & 1ull)   { ax |= v3.x; ay |= v3.y; }
      if ((keepB >> g0) & 1ull)        { ax |= v4.x; ay |= v4.y; }
      if ((keepB >> (g0+16)) & 1ull)   { ax |= v5.x; ay |= v5.y; }
      if ((keepB >> (g0+32)) & 1ull)   { ax |= v6.x; ay |= v6.y; }
      if ((keepB >> (g0+48)) & 1ull)   { ax |= v7.x; ay |= v7.y; }
      const int w0 = 2 * p0;
      if (ax) atomicOr(&rem[w0], ax);
      if (ay) atomicOr(&rem[w0 + 1], ay);
    }
    // next iteration's barrier_nodrain (lgkmcnt(0)) orders these ORs
    // before the rem reads
  }
  if (tid == 0) cnt[1] = (unsigned int)K;
}

// Fallback (small workspace): on-the-fly IoU greedy scan in one block.
__global__ __launch_bounds__(256) void k_scan_nomask(
    const float* __restrict__ sx1, const float* __restrict__ sy1,
    const float* __restrict__ sx2, const float* __restrict__ sy2,
    const float* __restrict__ sarea,
    unsigned int* __restrict__ cnt,
    unsigned int* __restrict__ keeps) {
  __shared__ unsigned char sup[NCAP];
  __shared__ int sK;
  int tid = threadIdx.x;
  int F = (int)cnt[0];
  for (int j = tid; j < NCAP; j += 256) sup[j] = 0;
  if (tid == 0) sK = 0;
  __syncthreads();
  for (int i = 0; i < F; ++i) {
    if (!sup[i]) {
      if (tid == 0) keeps[sK++] = (unsigned int)i;
      float xi1 = sx1[i], yi1 = sy1[i], xi2 = sx2[i], yi2 = sy2[i], ai = sarea[i];
      for (int j = i + 1 + tid; j < F; j += 256) {
        if (sup[j]) continue;
        float xx1 = fmaxf(xi1, sx1[j]);
        float yy1 = fmaxf(yi1, sy1[j]);
        float xx2 = fminf(xi2, sx2[j]);
        float yy2 = fminf(yi2, sy2[j]);
        float w = fmaxf(xx2 - xx1, 0.0f);
        float h = fmaxf(yy2 - yy1, 0.0f);
        float inter = w * h;
        float iou = inter / (ai + sarea[j] - inter);
        if (iou > 0.5f) sup[j] = 1;
      }
    }
    __syncthreads();
  }
  if (tid == 0) cnt[1] = (unsigned int)sK;
}

// ---------------------------------------------------------------------------
// Per class: top-KT over M kept boxes, REGISTER-RESIDENT (R13, unchanged).
// ---------------------------------------------------------------------------
__global__ __launch_bounds__(1024) void k_topk(
    const float* __restrict__ conf,
    const unsigned int* __restrict__ sorig,
    const unsigned int* __restrict__ keeps,
    const unsigned int* __restrict__ cnt,
    int C, int KT,
    float* __restrict__ topv, int* __restrict__ topi) {
  __shared__ float wlv[16];
  __shared__ int wli[16];
  __shared__ float ldsWv;
  __shared__ int ldsWj;
  const int tid = threadIdx.x;
  const int lane = tid & 63;
  const int wv_ = tid >> 6;
  const int c = blockIdx.x;
  const int M = (int)cnt[1];

  const float NEG = -3.402823466e+38f;
  float v[8];
#pragma unroll
  for (int k = 0; k < 8; ++k) {
    int j = tid + (k << 10);
    v[k] = (j < M) ? conf[(size_t)sorig[keeps[j]] * C + c] : NEG;
  }
  float bv = NEG; int bk_ = -1;
#pragma unroll
  for (int k = 0; k < 8; ++k)
    if (v[k] > bv) { bv = v[k]; bk_ = k; }
  int bj = (bk_ >= 0) ? (tid + (bk_ << 10)) : 0x7FFFFFFF;
  if (bv == NEG) bj = 0x7FFFFFFF;

  for (int t = 0; t < KT; ++t) {
    float rv = bv; int rj = bj;
#pragma unroll
    for (int off = 32; off; off >>= 1) {
      float v2 = __shfl_down(rv, off);
      int   j2 = __shfl_down(rj, off);
      if (v2 > rv || (v2 == rv && j2 < rj)) { rv = v2; rj = j2; }
    }
    if (lane == 0) { wlv[wv_] = rv; wli[wv_] = rj; }
    __syncthreads();
    if (wv_ == 0) {
      float fv = (lane < 16) ? wlv[lane] : NEG;
      int   fj = (lane < 16) ? wli[lane] : 0x7FFFFFFF;
#pragma unroll
      for (int off = 32; off; off >>= 1) {
        float v2 = __shfl_down(fv, off);
        int   j2 = __shfl_down(fj, off);
        if (v2 > fv || (v2 == fv && j2 < fj)) { fv = v2; fj = j2; }
      }
      if (lane == 0) {
        ldsWv = fv; ldsWj = fj;
        topv[c * KT + t] = fv;
        topi[c * KT + t] = (fj == 0x7FFFFFFF) ? 0 : fj;  // M<KT safety
      }
    }
    __syncthreads();
    const int wj = ldsWj;
    if (wj != 0x7FFFFFFF && (wj & 1023) == tid) {
      int kk = wj >> 10;
#pragma unroll
      for (int k = 0; k < 8; ++k)
        if (k == kk) v[k] = NEG;
      bv = NEG; bk_ = -1;
#pragma unroll
      for (int k = 0; k < 8; ++k)
        if (v[k] > bv) { bv = v[k]; bk_ = k; }
      bj = (bk_ >= 0) ? (tid + (bk_ << 10)) : 0x7FFFFFFF;
      if (bv == NEG) bj = 0x7FFFFFFF;
    }
  }
}

// Final scalar: smooth-L1 over (KT, C, 4) gathered boxes + focal CE on
// (class0 top-KT > 0.5), divided by M.
__global__ __launch_bounds__(256) void k_loss(
    const float* __restrict__ loc, const float* __restrict__ tb,
    const int* __restrict__ labels,
    const unsigned int* __restrict__ sorig,
    const unsigned int* __restrict__ keeps,
    const float* __restrict__ topv, const int* __restrict__ topi,
    const unsigned int* __restrict__ cnt, int C, int KT,
    float* __restrict__ out) {
  __shared__ float red[256];
  int tid = threadIdx.x;
  int F = (int)cnt[0];
  int M = (int)cnt[1];
  if (F == 0 || M == 0) {
    if (tid == 0) out[0] = 0.001f;
    return;
  }
  int total = KT * C * 4;
  float part = 0.0f;
  for (int e = tid; e < total; e += 256) {
    int d = e & 3;
    int q = e >> 2;
    int c = q % C;
    int i = q / C;
    int j = topi[c * KT + i];
    unsigned int orow = sorig[keeps[j]];
    float pred = loc[(size_t)orow * 4 + d];
    float tg = tb[c * 4 + d];
    float dd = fabsf(pred - tg);
    part += (dd < 1.0f) ? (0.5f * dd * dd) : (dd - 0.5f);
  }
  red[tid] = part;
  __syncthreads();
  for (int s = 128; s > 0; s >>= 1) {
    if (tid < s) red[tid] += red[tid + s];
    __syncthreads();
  }
  if (tid == 0) {
    float loc_loss = red[0];
    float mx = -3.402823466e+38f;
    for (int i = 0; i < KT; ++i) {
      float x = (topv[i] > 0.5f) ? 1.0f : 0.0f;   // class 0 column
      mx = fmaxf(mx, x);
    }
    float ssum = 0.0f;
    for (int i = 0; i < KT; ++i) {
      float x = (topv[i] > 0.5f) ? 1.0f : 0.0f;
      ssum += expf(x - mx);
    }
    float lse = mx + logf(ssum);
    float ce = 0.0f;
    for (int i = 0; i < KT; ++i) {
      float x = (topv[i] > 0.5f) ? 1.0f : 0.0f;
      ce += (float)labels[i] * (x - lse);
    }
    ce = -ce;
    float pt = expf(-ce);
    float om = 1.0f - pt;
    float conf_loss = 0.25f * om * om * ce;   // ALPHA=0.25, GAMMA=2
    out[0] = (loc_loss + conf_loss) / (float)M;
  }
}

// ---------------- host ------------------------------------------------------

extern "C" void kernel_launch(void* const* d_in, const int* in_sizes, int n_in,
                              void* d_out, int out_size, void* d_ws, size_t ws_size,
                              hipStream_t stream) {
  (void)n_in; (void)out_size;
  const float* loc    = (const float*)d_in[0];
  const float* conf   = (const float*)d_in[1];
  const float* tb     = (const float*)d_in[2];
  const int*   labels = (const int*)d_in[3];
  float* out = (float*)d_out;

  int N = in_sizes[0] / 4;
  if (N > NCAP) N = NCAP;
  int C  = (N > 0) ? (in_sizes[1] / N) : 20;
  int KT = in_sizes[3];

  char* ws = (char*)d_ws;
  unsigned int* cnt   = (unsigned int*)(ws + OFF_CNT);
  u64*          keys  = (u64*)(ws + OFF_KEYS);
  float*        sx1   = (float*)(ws + OFF_SX1);
  float*        sy1   = (float*)(ws + OFF_SY1);
  float*        sx2   = (float*)(ws + OFF_SX2);
  float*        sy2   = (float*)(ws + OFF_SY2);
  float*        sarea = (float*)(ws + OFF_AREA);
  unsigned int* sorig = (unsigned int*)(ws + OFF_SORIG);
  unsigned int* keeps = (unsigned int*)(ws + OFF_KEEPS);
  float*        topv  = (float*)(ws + OFF_TOPV);
  int*          topi  = (int*)(ws + OFF_TOPI);
  u64*          diagI = (u64*)(ws + OFF_DIAG2);
  u64*          mask  = (u64*)(ws + OFF_MASK);

  bool use_mask = (ws_size >= WS_NEED_MASK);

  k_psort<<<16, 64, 0, stream>>>(conf, N, C, keys);
  k_merge<<<1, 1024, 0, stream>>>(loc, keys, cnt,
                                  sx1, sy1, sx2, sy2, sarea, sorig);
  if (use_mask) {
    k_mask<<<dim3(WROW, WROW), 64, 0, stream>>>(sx1, sy1, sx2, sy2, sarea,
                                                mask, diagI);
    k_scan<<<1, 1024, 0, stream>>>(mask, diagI, cnt, keeps);
  } else {
    k_scan_nomask<<<1, 256, 0, stream>>>(sx1, sy1, sx2, sy2, sarea, cnt, keeps);
  }
  k_topk<<<C, 1024, 0, stream>>>(conf, sorig, keeps, cnt, C, KT, topv, topi);
  k_loss<<<1, 256, 0, stream>>>(loc, tb, labels, sorig, keeps, topv, topi, cnt, C, KT, out);
}

// Round 8
// 299.645 us; speedup vs baseline: 1.0638x; 1.0271x over previous
//
#include <hip/hip_runtime.h>
#include <stdint.h>
#include <stddef.h>

// ---------------------------------------------------------------------------
// BoundingBox loss processor:
//   filter (maxconf > 0.6) -> sort by class-0 score desc (stable, idx asc)
//   -> greedy NMS (IoU > 0.5 suppress) -> per-class top-20 over kept
//   -> smooth-L1 sum + focal CE on (class0 top-20 > 0.5) -> /M
//
// Journal: R10 involved-set greedy. R13 register topk. R14 pre-OR atomics.
// R15 128-row chunks. R17 short wave-0 segment. R18 sort split.
// R19 NULL: no-drain barriers — loads already hidden.
// R20/R21 WIN: DPP wave-OR, k_scan 137->99.8us.
// R24 FAIL: sparsity gate -6x bytes but +15us (gate load serialized issue).
// R25 FAIL: redundant greedy + 1 barrier: 103.4us (issue-bound > latency-bound).
// => k_scan floor ~100us in this structure; 3 levers all <=+-15%. PINNED at
// R21-exact (2 nodrain barriers, wave-0 greedy, wave-1 keeps store).
// R26: attack the OTHER ~205us. k_psort loaded conf with 20 SCALAR dword
// loads/row (160/lane, 16 CUs only) — classic missed vectorization; all 20
// floats ARE consumed (max + cr[0]) so float4 x5 is fully efficient (row
// stride 80B, 16B-aligned). k_merge gather: loc row = 16B -> one float4.
// ---------------------------------------------------------------------------

#define NCAP 8192
#define WROW (NCAP / 64)   // 128 u64 words per mask row

typedef unsigned long long u64;

// ---------------- workspace layout (all offsets 16-byte aligned) -----------
constexpr size_t OFF_CNT   = 0;                               // 2 x u32: [0]=F, [1]=M
constexpr size_t OFF_KEYS  = 256;                             // u64[NCAP] (psort->merge)
constexpr size_t OFF_SX1   = OFF_KEYS + 8ull * NCAP;          // f32[NCAP]
constexpr size_t OFF_SY1   = OFF_SX1 + 4ull * NCAP;
constexpr size_t OFF_SX2   = OFF_SY1 + 4ull * NCAP;
constexpr size_t OFF_SY2   = OFF_SX2 + 4ull * NCAP;
constexpr size_t OFF_AREA  = OFF_SY2 + 4ull * NCAP;
constexpr size_t OFF_SORIG = OFF_AREA + 4ull * NCAP;          // u32[NCAP]
constexpr size_t OFF_KEEPS = OFF_SORIG + 4ull * NCAP;         // u32[NCAP]
constexpr size_t OFF_KORIG = OFF_KEEPS + 4ull * NCAP;         // u32[NCAP] (unused)
constexpr size_t OFF_TOPV  = OFF_KORIG + 4ull * NCAP;         // f32[1024]
constexpr size_t OFF_TOPI  = OFF_TOPV + 4096;                 // i32[1024]
constexpr size_t OFF_DIAG2 = OFF_TOPI + 4096;                 // u64[2*NCAP] = 128 KB, interleaved
constexpr size_t OFF_MASK  = OFF_DIAG2 + 16ull * NCAP;        // u64[NCAP*WROW] = 8 MB
constexpr size_t WS_NEED_MASK = OFF_MASK + 8ull * NCAP * WROW;

// Barrier that does NOT drain vmcnt: LDS-only wait + raw s_barrier.
__device__ __forceinline__ void barrier_nodrain() {
  asm volatile("s_waitcnt lgkmcnt(0)" ::: "memory");
  __builtin_amdgcn_s_barrier();
  asm volatile("" ::: "memory");
}

// ---- DPP full-wave OR reduce (R20/R21) ------------------------------------
template <int CTRL, int RMASK>
__device__ __forceinline__ unsigned or_dpp_step(unsigned x) {
  return x | (unsigned)__builtin_amdgcn_update_dpp(0, (int)x, CTRL, RMASK, 0xf, true);
}
__device__ __forceinline__ u64 wave_or64(u64 x) {
  unsigned lo = (unsigned)x, hi = (unsigned)(x >> 32);
  lo = or_dpp_step<0x111, 0xf>(lo); hi = or_dpp_step<0x111, 0xf>(hi);  // row_shr:1
  lo = or_dpp_step<0x112, 0xf>(lo); hi = or_dpp_step<0x112, 0xf>(hi);  // row_shr:2
  lo = or_dpp_step<0x114, 0xf>(lo); hi = or_dpp_step<0x114, 0xf>(hi);  // row_shr:4
  lo = or_dpp_step<0x118, 0xf>(lo); hi = or_dpp_step<0x118, 0xf>(hi);  // row_shr:8
  lo = or_dpp_step<0x142, 0xa>(lo); hi = or_dpp_step<0x142, 0xa>(hi);  // row_bcast:15
  lo = or_dpp_step<0x143, 0xc>(lo); hi = or_dpp_step<0x143, 0xc>(hi);  // row_bcast:31
  lo = (unsigned)__builtin_amdgcn_readlane((int)lo, 63);
  hi = (unsigned)__builtin_amdgcn_readlane((int)hi, 63);
  return ((u64)hi << 32) | lo;
}

// ---------------- bitonic building blocks (shared by k_psort / k_merge) ----
#define SS1(M)                                                              \
  { int tt = base + (M) * 64 + l;                                           \
    u64 a = e[M];                                                           \
    unsigned slo = __shfl_xor((unsigned)a, (int)jj);                        \
    unsigned shi = __shfl_xor((unsigned)(a >> 32), (int)jj);                \
    u64 b = ((u64)shi << 32) | slo;                                         \
    bool up = ((tt & bk) == 0);                                             \
    bool lowr = ((l & (int)jj) == 0);                                       \
    bool tmin = (up == lowr);                                               \
    bool agtb = (a > b);                                                    \
    e[M] = (tmin == agtb) ? b : a; }

#define SSTEP() { SS1(0) SS1(1) SS1(2) SS1(3) SS1(4) SS1(5) SS1(6) SS1(7) }

#define CSW(A, B)                                                           \
  { int tt = base + (A) * 64 + l;                                           \
    bool up = ((tt & bk) == 0);                                             \
    u64 xa = e[A], xb = e[B];                                               \
    bool sw = up ? (xa > xb) : (xa < xb);                                   \
    e[A] = sw ? xb : xa; e[B] = sw ? xa : xb; }

#define RSTEP4() { CSW(0,4) CSW(1,5) CSW(2,6) CSW(3,7) }
#define RSTEP2() { CSW(0,2) CSW(1,3) CSW(4,6) CSW(5,7) }
#define RSTEP1() { CSW(0,1) CSW(2,3) CSW(4,5) CSW(6,7) }

// ---------------------------------------------------------------------------
// Parallel pre-sort: 16 blocks x 1 wave; block b builds keys for rows
// [512b, 512b+512) and runs bitonic phases bk=2..512. R26: conf row loads
// vectorized to float4 (5 loads/row vs 20 scalar; row stride 80B is 16B-
// aligned; every float is consumed by the max/key).
// ---------------------------------------------------------------------------
__global__ __launch_bounds__(64) void k_psort(
    const float* __restrict__ conf, int N, int C,
    u64* __restrict__ keys) {
  const int l = threadIdx.x;
  const int base = blockIdx.x * 512;
  const bool vec4 = ((C & 3) == 0);
  u64 e[8];
#pragma unroll
  for (int m = 0; m < 8; ++m) {
    int row = base + m * 64 + l;
    u64 key;
    if (row < N) {
      const float* cr = conf + (size_t)row * C;
      float mx, c0;
      if (vec4) {
        const float4* cr4 = (const float4*)cr;
        float4 q = cr4[0];
        c0 = q.x;
        mx = fmaxf(fmaxf(q.x, q.y), fmaxf(q.z, q.w));
        for (int k = 1; k < (C >> 2); ++k) {
          float4 p = cr4[k];
          mx = fmaxf(mx, fmaxf(fmaxf(p.x, p.y), fmaxf(p.z, p.w)));
        }
      } else {
        c0 = cr[0];
        mx = c0;
        for (int c = 1; c < C; ++c) mx = fmaxf(mx, cr[c]);
      }
      unsigned int k32;
      if (mx > 0.6f) {
        union { float f; unsigned int u; } s; s.f = c0;
        unsigned int u = s.u;
        u = (u & 0x80000000u) ? ~u : (u | 0x80000000u);  // monotone map
        k32 = ~u;                                        // descending
        if (k32 == 0xFFFFFFFFu) k32 = 0xFFFFFFFEu;       // reserve invalid
      } else {
        k32 = 0xFFFFFFFFu;
      }
      key = ((u64)k32 << 32) | (unsigned int)row;
    } else {
      key = ((u64)0xFFFFFFFFu << 32);
    }
    e[m] = key;
  }
  for (unsigned bk = 2; bk <= 512; bk <<= 1) {
    unsigned j = bk >> 1;
    if (j == 256) { RSTEP4(); j = 128; }
    if (j == 128) { RSTEP2(); j = 64; }
    if (j == 64)  { RSTEP1(); j = 32; }
    for (unsigned jj = j; jj >= 1; jj >>= 1) SSTEP();
  }
#pragma unroll
  for (int m = 0; m < 8; ++m) keys[base + m * 64 + l] = e[m];
}

// ---------------------------------------------------------------------------
// Merge phases bk=1024..8192 (one block) + count/gather epilogue.
// R26: loc gather vectorized (one float4 per row, 16B-aligned).
// ---------------------------------------------------------------------------
__global__ __launch_bounds__(1024) void k_merge(
    const float* __restrict__ loc,
    u64* __restrict__ keys, unsigned int* __restrict__ cnt,
    float* __restrict__ sx1, float* __restrict__ sy1,
    float* __restrict__ sx2, float* __restrict__ sy2,
    float* __restrict__ sarea, unsigned int* __restrict__ sorig) {
  __shared__ u64 sk[NCAP];  // 64 KiB (j>=512 sessions)
  __shared__ int wsum[16];
  const int tid = threadIdx.x;
  const int w = tid >> 6, l = tid & 63;
  const int base = w * 512;
  u64 e[8];
#pragma unroll
  for (int m = 0; m < 8; ++m) e[m] = keys[base + m * 64 + l];

  for (unsigned bk = 1024; bk <= NCAP; bk <<= 1) {
    unsigned j = bk >> 1;   // >= 512 always
    {
#pragma unroll
      for (int m = 0; m < 8; ++m) sk[base + m * 64 + l] = e[m];
      __syncthreads();
      for (unsigned j2 = bk >> 1; j2 >= 512; j2 >>= 1) {
        for (int tl = tid; tl < NCAP; tl += 1024) {
          unsigned p = (unsigned)tl ^ j2;
          if (p > (unsigned)tl) {
            bool up = ((tl & bk) == 0);
            u64 x = sk[tl], y = sk[p];
            bool sw = up ? (x > y) : (x < y);
            if (sw) { sk[tl] = y; sk[p] = x; }
          }
        }
        __syncthreads();
      }
#pragma unroll
      for (int m = 0; m < 8; ++m) e[m] = sk[base + m * 64 + l];
      __syncthreads();   // protect sk reads from next session's writes
      j = 256;
    }
    if (j == 256) { RSTEP4(); j = 128; }
    if (j == 128) { RSTEP2(); j = 64; }
    if (j == 64)  { RSTEP1(); j = 32; }
    for (unsigned jj = j; jj >= 1; jj >>= 1) SSTEP();
  }

  // epilogue: count valid + fused gather (float4)
  int cv = 0;
#pragma unroll
  for (int m = 0; m < 8; ++m) {
    int idx = base + m * 64 + l;
    u64 key = e[m];
    if ((key >> 32) != 0xFFFFFFFFull) ++cv;
    unsigned row = (unsigned)(key & 0xFFFFFFFFull);
    float4 b4 = *(const float4*)(loc + (size_t)row * 4);
    float x1 = b4.x, y1 = b4.y, x2 = b4.z, y2 = b4.w;
    sx1[idx] = x1; sy1[idx] = y1; sx2[idx] = x2; sy2[idx] = y2;
    sarea[idx] = (x2 - x1) * (y2 - y1);   // numpy op order, no FMA hazard
    sorig[idx] = row;
  }
  for (int off = 32; off; off >>= 1) cv += __shfl_down(cv, off);
  if (l == 0) wsum[w] = cv;
  __syncthreads();
  if (tid == 0) {
    int s = 0;
    for (int i = 0; i < 16; ++i) s += wsum[i];
    cnt[0] = (unsigned int)s;
  }
}

// Pairwise IoU>0.5 bitmask, 64x64 tiles, 1 wave per block.
// Skip by < (bx & ~1) (never consumed). Diagonal-super blocks write the
// INTERLEAVED diag strip: diagI[2*i + (by&1)].
__global__ __launch_bounds__(64) void k_mask(
    const float* __restrict__ sx1, const float* __restrict__ sy1,
    const float* __restrict__ sx2, const float* __restrict__ sy2,
    const float* __restrict__ sarea,
    u64* __restrict__ mask, u64* __restrict__ diagI) {
  if (blockIdx.y < (blockIdx.x & ~1u)) return;
  __shared__ float jx1[64], jy1[64], jx2[64], jy2[64], ja[64];
  int t = threadIdx.x;
  int jbase = blockIdx.y * 64;
  jx1[t] = sx1[jbase + t]; jy1[t] = sy1[jbase + t];
  jx2[t] = sx2[jbase + t]; jy2[t] = sy2[jbase + t];
  ja[t]  = sarea[jbase + t];
  __syncthreads();
  int i = blockIdx.x * 64 + t;
  float xi1 = sx1[i], yi1 = sy1[i], xi2 = sx2[i], yi2 = sy2[i], ai = sarea[i];
  u64 bits = 0ULL;
#pragma unroll 8
  for (int jj = 0; jj < 64; ++jj) {
    float xx1 = fmaxf(xi1, jx1[jj]);
    float yy1 = fmaxf(yi1, jy1[jj]);
    float xx2 = fminf(xi2, jx2[jj]);
    float yy2 = fminf(yi2, jy2[jj]);
    float w = fmaxf(xx2 - xx1, 0.0f);
    float h = fmaxf(yy2 - yy1, 0.0f);
    float inter = w * h;
    float den = ai + ja[jj] - inter;   // (ai + aj) - inter, numpy order
    float iou = inter / den;           // IEEE div; 0/0 -> NaN -> compare false
    if (iou > 0.5f) bits |= (1ULL << jj);
  }
  mask[(size_t)i * WROW + blockIdx.y] = bits;
  if ((blockIdx.y >> 1) == (blockIdx.x >> 1))
    diagI[((size_t)i << 1) + (blockIdx.y & 1)] = bits;
}

// ---------------------------------------------------------------------------
// Chunked greedy scan — R21-EXACT (measured 99.8us): R17 algorithm, R19
// nodrain barriers, R20/R21 DPP wave-OR. PINNED — R24 (gating) and R25
// (redundant greedy) both regressed; do not perturb.
// ---------------------------------------------------------------------------
__global__ __launch_bounds__(1024) void k_scan(
    const u64* __restrict__ mask,
    const u64* __restrict__ diagIg,
    unsigned int* __restrict__ cnt,
    unsigned int* __restrict__ keeps) {
  __shared__ __align__(16) u64 ldsDiag[2 * NCAP];   // 128 KB, interleaved
  __shared__ __align__(16) u64 rem[WROW];           // removed-set (1 KB)
  __shared__ u64 ldsKA, ldsKB;
  __shared__ int ldsKb;
  const int tid = threadIdx.x;
  const int F = (int)cnt[0];
  const int nch = (F + 127) >> 7;
  const ulonglong2* __restrict__ m2 = (const ulonglong2*)mask;  // 64 pairs/row

  for (int i = tid; i < 2 * NCAP; i += 1024) ldsDiag[i] = diagIg[i];
  for (int w = tid; w < WROW; w += 1024) rem[w] = 0;

  const int p0 = tid & 63;    // pair index (words 2p0, 2p0+1) of held rows
  const int g0 = tid >> 6;    // row group: rows g0 + 16k (k<8) of each chunk
  int K = 0;
  __syncthreads();            // staging + rem init visible (full drain ok, once)

  for (int H = 0; H < nch; ++H) {
    const size_t gb = (size_t)H * 8192;   // chunk = 8192 linear 16B units
    const int base = H << 7;
    const bool ld = (p0 > H);             // both words >= 2H+2
    ulonglong2 v0 = {0,0}, v1 = {0,0}, v2 = {0,0}, v3 = {0,0},
               v4 = {0,0}, v5 = {0,0}, v6 = {0,0}, v7 = {0,0};
    if (ld) {
      v0 = m2[gb + tid];
      v1 = m2[gb + tid + 1024];
      v2 = m2[gb + tid + 2048];
      v3 = m2[gb + tid + 3072];
      v4 = m2[gb + tid + 4096];
      v5 = m2[gb + tid + 5120];
      v6 = m2[gb + tid + 6144];
      v7 = m2[gb + tid + 7168];
    }
    barrier_nodrain();   // prev chunk's rem ORs visible; loads stay in flight

    if (tid < 64) {
      // 3 LDS reads total: (DA,AB) b128, DB, (sup0,supB0) b128
      ulonglong2 dAB = *(const ulonglong2*)&ldsDiag[(size_t)(base + tid) << 1];
      u64 DA = dAB.x, AB = dAB.y;
      u64 DB = ldsDiag[(((size_t)(base + 64 + tid)) << 1) + 1];
      ulonglong2 supP = *(const ulonglong2*)&rem[2 * H];
      u64 sup0 = supP.x, supB0 = supP.y;

      int remrows = F - base;
      u64 validA = (remrows >= 64) ? ~0ull : ((1ull << remrows) - 1ull);
      int r2 = remrows - 64;
      u64 validB = (r2 >= 64) ? ~0ull : ((r2 <= 0) ? 0ull : ((1ull << r2) - 1ull));

      // ---- sub-greedy A (R10 involved-set shortcut) ----
      u64 DfwdA = (tid < 63) ? (DA & (~0ull << (tid + 1))) : 0ull;
      u64 undec = validA & ~sup0;
      u64 dmask = ((undec >> tid) & 1ull) ? DfwdA : 0ull;
      u64 vuln = wave_or64(dmask);
      u64 dang = __ballot(dmask != 0ull);
      u64 involved = (dang | vuln) & undec;
      u64 keepA = undec & ~involved;
      u64 und2 = involved;
      {
        unsigned Flo = (unsigned)DfwdA, Fhi = (unsigned)(DfwdA >> 32);
        while (und2) {
          int rr = __builtin_ctzll(und2);
          keepA |= 1ull << rr;
          unsigned dlo = __builtin_amdgcn_readlane(Flo, rr);
          unsigned dhi = __builtin_amdgcn_readlane(Fhi, rr);
          und2 &= ~((((u64)dhi << 32) | (u64)dlo) | (1ull << rr));
        }
      }

      // ---- A -> B suppression, then sub-greedy B ----
      u64 abm = ((keepA >> tid) & 1ull) ? AB : 0ull;
      u64 supB = supB0 | wave_or64(abm);
      u64 DfwdB = (tid < 63) ? (DB & (~0ull << (tid + 1))) : 0ull;
      u64 undecB = validB & ~supB;
      u64 dmaskB = ((undecB >> tid) & 1ull) ? DfwdB : 0ull;
      u64 vulnB = wave_or64(dmaskB);
      u64 dangB = __ballot(dmaskB != 0ull);
      u64 involvedB = (dangB | vulnB) & undecB;
      u64 keepB = undecB & ~involvedB;
      u64 und2B = involvedB;
      {
        unsigned Flo = (unsigned)DfwdB, Fhi = (unsigned)(DfwdB >> 32);
        while (und2B) {
          int rr = __builtin_ctzll(und2B);
          keepB |= 1ull << rr;
          unsigned dlo = __builtin_amdgcn_readlane(Flo, rr);
          unsigned dhi = __builtin_amdgcn_readlane(Fhi, rr);
          und2B &= ~((((u64)dhi << 32) | (u64)dlo) | (1ull << rr));
        }
      }

      if (tid == 0) { ldsKA = keepA; ldsKB = keepB; ldsKb = K; }
      K += __popcll(keepA) + __popcll(keepB);   // uniform; stores by wave 1
    }
    barrier_nodrain();   // ldsKA/ldsKB/ldsKb visible; loads still in flight

    const u64 keepA = ldsKA, keepB = ldsKB;

    // ---- keeps store by WAVE 1 (off wave-0's serial segment) ----
    if (g0 == 1) {
      const int l = p0;
      const int Kb = ldsKb;
      int pcA = __popcll(keepA);
      unsigned kloA = (unsigned)keepA, khiA = (unsigned)(keepA >> 32);
      int preA = __builtin_amdgcn_mbcnt_hi(khiA, __builtin_amdgcn_mbcnt_lo(kloA, 0));
      if ((keepA >> l) & 1ull) keeps[Kb + preA] = (unsigned)(base + l);
      unsigned kloB = (unsigned)keepB, khiB = (unsigned)(keepB >> 32);
      int preB = __builtin_amdgcn_mbcnt_hi(khiB, __builtin_amdgcn_mbcnt_lo(kloB, 0));
      if ((keepB >> l) & 1ull) keeps[Kb + pcA + preB] = (unsigned)(base + 64 + l);
    }

    if (ld && (keepA | keepB)) {
      u64 ax = 0, ay = 0;                  // register pre-OR (R14)
      if ((keepA >> g0) & 1ull)        { ax |= v0.x; ay |= v0.y; }
      if ((keepA >> (g0+16)) & 1ull)   { ax |= v1.x; ay |= v1.y; }
      if ((keepA >> (g0+32)) & 1ull)   { ax |= v2.x; ay |= v2.y; }
      if ((keepA >> (g0+48)) & 1ull)   { ax |= v3.x; ay |= v3.y; }
      if ((keepB >> g0) & 1ull)        { ax |= v4.x; ay |= v4.y; }
      if ((keepB >> (g0+16)) & 1ull)   { ax |= v5.x; ay |= v5.y; }
      if ((keepB >> (g0+32)) & 1ull)   { ax |= v6.x; ay |= v6.y; }
      if ((keepB >> (g0+48)) & 1ull)   { ax |= v7.x; ay |= v7.y; }
      const int w0 = 2 * p0;
      if (ax) atomicOr(&rem[w0], ax);
      if (ay) atomicOr(&rem[w0 + 1], ay);
    }
    // next iteration's barrier_nodrain (lgkmcnt(0)) orders these ORs
    // before the rem reads
  }
  if (tid == 0) cnt[1] = (unsigned int)K;
}

// Fallback (small workspace): on-the-fly IoU greedy scan in one block.
__global__ __launch_bounds__(256) void k_scan_nomask(
    const float* __restrict__ sx1, const float* __restrict__ sy1,
    const float* __restrict__ sx2, const float* __restrict__ sy2,
    const float* __restrict__ sarea,
    unsigned int* __restrict__ cnt,
    unsigned int* __restrict__ keeps) {
  __shared__ unsigned char sup[NCAP];
  __shared__ int sK;
  int tid = threadIdx.x;
  int F = (int)cnt[0];
  for (int j = tid; j < NCAP; j += 256) sup[j] = 0;
  if (tid == 0) sK = 0;
  __syncthreads();
  for (int i = 0; i < F; ++i) {
    if (!sup[i]) {
      if (tid == 0) keeps[sK++] = (unsigned int)i;
      float xi1 = sx1[i], yi1 = sy1[i], xi2 = sx2[i], yi2 = sy2[i], ai = sarea[i];
      for (int j = i + 1 + tid; j < F; j += 256) {
        if (sup[j]) continue;
        float xx1 = fmaxf(xi1, sx1[j]);
        float yy1 = fmaxf(yi1, sy1[j]);
        float xx2 = fminf(xi2, sx2[j]);
        float yy2 = fminf(yi2, sy2[j]);
        float w = fmaxf(xx2 - xx1, 0.0f);
        float h = fmaxf(yy2 - yy1, 0.0f);
        float inter = w * h;
        float iou = inter / (ai + sarea[j] - inter);
        if (iou > 0.5f) sup[j] = 1;
      }
    }
    __syncthreads();
  }
  if (tid == 0) cnt[1] = (unsigned int)sK;
}

// ---------------------------------------------------------------------------
// Per class: top-KT over M kept boxes, REGISTER-RESIDENT (R13, unchanged).
// ---------------------------------------------------------------------------
__global__ __launch_bounds__(1024) void k_topk(
    const float* __restrict__ conf,
    const unsigned int* __restrict__ sorig,
    const unsigned int* __restrict__ keeps,
    const unsigned int* __restrict__ cnt,
    int C, int KT,
    float* __restrict__ topv, int* __restrict__ topi) {
  __shared__ float wlv[16];
  __shared__ int wli[16];
  __shared__ float ldsWv;
  __shared__ int ldsWj;
  const int tid = threadIdx.x;
  const int lane = tid & 63;
  const int wv_ = tid >> 6;
  const int c = blockIdx.x;
  const int M = (int)cnt[1];

  const float NEG = -3.402823466e+38f;
  float v[8];
#pragma unroll
  for (int k = 0; k < 8; ++k) {
    int j = tid + (k << 10);
    v[k] = (j < M) ? conf[(size_t)sorig[keeps[j]] * C + c] : NEG;
  }
  float bv = NEG; int bk_ = -1;
#pragma unroll
  for (int k = 0; k < 8; ++k)
    if (v[k] > bv) { bv = v[k]; bk_ = k; }
  int bj = (bk_ >= 0) ? (tid + (bk_ << 10)) : 0x7FFFFFFF;
  if (bv == NEG) bj = 0x7FFFFFFF;

  for (int t = 0; t < KT; ++t) {
    float rv = bv; int rj = bj;
#pragma unroll
    for (int off = 32; off; off >>= 1) {
      float v2 = __shfl_down(rv, off);
      int   j2 = __shfl_down(rj, off);
      if (v2 > rv || (v2 == rv && j2 < rj)) { rv = v2; rj = j2; }
    }
    if (lane == 0) { wlv[wv_] = rv; wli[wv_] = rj; }
    __syncthreads();
    if (wv_ == 0) {
      float fv = (lane < 16) ? wlv[lane] : NEG;
      int   fj = (lane < 16) ? wli[lane] : 0x7FFFFFFF;
#pragma unroll
      for (int off = 32; off; off >>= 1) {
        float v2 = __shfl_down(fv, off);
        int   j2 = __shfl_down(fj, off);
        if (v2 > fv || (v2 == fv && j2 < fj)) { fv = v2; fj = j2; }
      }
      if (lane == 0) {
        ldsWv = fv; ldsWj = fj;
        topv[c * KT + t] = fv;
        topi[c * KT + t] = (fj == 0x7FFFFFFF) ? 0 : fj;  // M<KT safety
      }
    }
    __syncthreads();
    const int wj = ldsWj;
    if (wj != 0x7FFFFFFF && (wj & 1023) == tid) {
      int kk = wj >> 10;
#pragma unroll
      for (int k = 0; k < 8; ++k)
        if (k == kk) v[k] = NEG;
      bv = NEG; bk_ = -1;
#pragma unroll
      for (int k = 0; k < 8; ++k)
        if (v[k] > bv) { bv = v[k]; bk_ = k; }
      bj = (bk_ >= 0) ? (tid + (bk_ << 10)) : 0x7FFFFFFF;
      if (bv == NEG) bj = 0x7FFFFFFF;
    }
  }
}

// Final scalar: smooth-L1 over (KT, C, 4) gathered boxes + focal CE on
// (class0 top-KT > 0.5), divided by M.
__global__ __launch_bounds__(256) void k_loss(
    const float* __restrict__ loc, const float* __restrict__ tb,
    const int* __restrict__ labels,
    const unsigned int* __restrict__ sorig,
    const unsigned int* __restrict__ keeps,
    const float* __restrict__ topv, const int* __restrict__ topi,
    const unsigned int* __restrict__ cnt, int C, int KT,
    float* __restrict__ out) {
  __shared__ float red[256];
  int tid = threadIdx.x;
  int F = (int)cnt[0];
  int M = (int)cnt[1];
  if (F == 0 || M == 0) {
    if (tid == 0) out[0] = 0.001f;
    return;
  }
  int total = KT * C * 4;
  float part = 0.0f;
  for (int e = tid; e < total; e += 256) {
    int d = e & 3;
    int q = e >> 2;
    int c = q % C;
    int i = q / C;
    int j = topi[c * KT + i];
    unsigned int orow = sorig[keeps[j]];
    float pred = loc[(size_t)orow * 4 + d];
    float tg = tb[c * 4 + d];
    float dd = fabsf(pred - tg);
    part += (dd < 1.0f) ? (0.5f * dd * dd) : (dd - 0.5f);
  }
  red[tid] = part;
  __syncthreads();
  for (int s = 128; s > 0; s >>= 1) {
    if (tid < s) red[tid] += red[tid + s];
    __syncthreads();
  }
  if (tid == 0) {
    float loc_loss = red[0];
    float mx = -3.402823466e+38f;
    for (int i = 0; i < KT; ++i) {
      float x = (topv[i] > 0.5f) ? 1.0f : 0.0f;   // class 0 column
      mx = fmaxf(mx, x);
    }
    float ssum = 0.0f;
    for (int i = 0; i < KT; ++i) {
      float x = (topv[i] > 0.5f) ? 1.0f : 0.0f;
      ssum += expf(x - mx);
    }
    float lse = mx + logf(ssum);
    float ce = 0.0f;
    for (int i = 0; i < KT; ++i) {
      float x = (topv[i] > 0.5f) ? 1.0f : 0.0f;
      ce += (float)labels[i] * (x - lse);
    }
    ce = -ce;
    float pt = expf(-ce);
    float om = 1.0f - pt;
    float conf_loss = 0.25f * om * om * ce;   // ALPHA=0.25, GAMMA=2
    out[0] = (loc_loss + conf_loss) / (float)M;
  }
}

// ---------------- host ------------------------------------------------------

extern "C" void kernel_launch(void* const* d_in, const int* in_sizes, int n_in,
                              void* d_out, int out_size, void* d_ws, size_t ws_size,
                              hipStream_t stream) {
  (void)n_in; (void)out_size;
  const float* loc    = (const float*)d_in[0];
  const float* conf   = (const float*)d_in[1];
  const float* tb     = (const float*)d_in[2];
  const int*   labels = (const int*)d_in[3];
  float* out = (float*)d_out;

  int N = in_sizes[0] / 4;
  if (N > NCAP) N = NCAP;
  int C  = (N > 0) ? (in_sizes[1] / N) : 20;
  int KT = in_sizes[3];

  char* ws = (char*)d_ws;
  unsigned int* cnt   = (unsigned int*)(ws + OFF_CNT);
  u64*          keys  = (u64*)(ws + OFF_KEYS);
  float*        sx1   = (float*)(ws + OFF_SX1);
  float*        sy1   = (float*)(ws + OFF_SY1);
  float*        sx2   = (float*)(ws + OFF_SX2);
  float*        sy2   = (float*)(ws + OFF_SY2);
  float*        sarea = (float*)(ws + OFF_AREA);
  unsigned int* sorig = (unsigned int*)(ws + OFF_SORIG);
  unsigned int* keeps = (unsigned int*)(ws + OFF_KEEPS);
  float*        topv  = (float*)(ws + OFF_TOPV);
  int*          topi  = (int*)(ws + OFF_TOPI);
  u64*          diagI = (u64*)(ws + OFF_DIAG2);
  u64*          mask  = (u64*)(ws + OFF_MASK);

  bool use_mask = (ws_size >= WS_NEED_MASK);

  k_psort<<<16, 64, 0, stream>>>(conf, N, C, keys);
  k_merge<<<1, 1024, 0, stream>>>(loc, keys, cnt,
                                  sx1, sy1, sx2, sy2, sarea, sorig);
  if (use_mask) {
    k_mask<<<dim3(WROW, WROW), 64, 0, stream>>>(sx1, sy1, sx2, sy2, sarea,
                                                mask, diagI);
    k_scan<<<1, 1024, 0, stream>>>(mask, diagI, cnt, keeps);
  } else {
    k_scan_nomask<<<1, 256, 0, stream>>>(sx1, sy1, sx2, sy2, sarea, cnt, keeps);
  }
  k_topk<<<C, 1024, 0, stream>>>(conf, sorig, keeps, cnt, C, KT, topv, topi);
  k_loss<<<1, 256, 0, stream>>>(loc, tb, labels, sorig, keeps, topv, topi, cnt, C, KT, out);
}